// Round 4
// baseline (546.454 us; speedup 1.0000x reference)
//
#include <hip/hip_runtime.h>
#include <stdint.h>

typedef __bf16 bf16;
typedef bf16 bf16x8 __attribute__((ext_vector_type(8)));
typedef float f32x4 __attribute__((ext_vector_type(4)));

#define N_NODES 131072
#define D_IN    128
#define KEXP    1024
#define H_DIM   512
#define NGRP    4
#define NPG     32768   // N_NODES / NGRP
#define F_SEG   8192
#define G_SEG   32
#define C_OUT   16

// async global->LDS DMA, 16B per lane; LDS dest = wave-uniform base + lane*16
typedef const __attribute__((address_space(1))) void* gas_t;
typedef __attribute__((address_space(3))) void* las_t;
__device__ __forceinline__ void cp16_async(const bf16* g, bf16* l) {
    __builtin_amdgcn_global_load_lds((gas_t)g, (las_t)l, 16, 0, 0);
}

// ---------------------------------------------------------------------------
// One-time weight cast + swizzle into MFMA-fragment order (16x16x32 bf16).
// B-frag layout: lane (quad=lane>>4, ln=lane&15) holds B[k=quad*8+j][n=ln].
//
// W1F[g][kc(16)][f=ks*4+nt (16)][slot=lane (64)][j (8)]
//     = W1[g][d = ks*32 + quad*8 + j][k' = kc*64 + nt*16 + ln]
// W2F[g][n0t2(2)][kc(16)][f=ks2*16+nt (32)][slot][j]      (N-tile = 256)
//     = W2[g][k = kc*64 + ks2*32 + quad*8 + j][n = n0t2*256 + nt*16 + ln]
// ---------------------------------------------------------------------------
__global__ void convert_weights(const float* __restrict__ W1,
                                const float* __restrict__ W2,
                                bf16* __restrict__ W1F,
                                bf16* __restrict__ W2F)
{
    int t = blockIdx.x * 256 + threadIdx.x;
    if (t < 65536) {
        int slot = t & 63, f = (t >> 6) & 15, kc = (t >> 10) & 15, g = t >> 14;
        int ks = f >> 2, nt = f & 3, quad = slot >> 4, ln = slot & 15;
        int k = kc * 64 + nt * 16 + ln;
        const float* src = W1 + ((size_t)(g * 128 + ks * 32 + quad * 8)) * 1024 + k;
        bf16x8 v;
        #pragma unroll
        for (int j = 0; j < 8; ++j) v[j] = (bf16)src[(size_t)j * 1024];
        *(bf16x8*)(W1F + (size_t)t * 8) = v;
    } else {
        int u = t - 65536;
        if (u < 262144) {
            int slot = u & 63, f = (u >> 6) & 31, kc = (u >> 11) & 15;
            int n0t2 = (u >> 15) & 1, g = u >> 16;
            int ks2 = f >> 4, nt = f & 15, quad = slot >> 4, ln = slot & 15;
            int k = kc * 64 + ks2 * 32 + quad * 8;
            int n = n0t2 * 256 + nt * 16 + ln;
            const float* src = W2 + ((size_t)(g * 1024 + k)) * 512 + n;
            bf16x8 v;
            #pragma unroll
            for (int j = 0; j < 8; ++j) v[j] = (bf16)src[(size_t)j * 512];
            *(bf16x8*)(W2F + (size_t)u * 8) = v;
        }
    }
}

// ---------------------------------------------------------------------------
// Fused gather + GEMM1(relu) + GEMM2 + scatter. 256 threads (4 waves).
// Round-4: tile 128 nodes x 256 of H (halves GEMM1 recompute: 275->206 GF).
//  - W2 B-frags read DIRECTLY from global (frag = coalesced dwordx4 at
//    base+lane*16); W2F is L2-resident (4 MB) and 4 waves/block share frags
//    via L1 -> W2 is off the LDS pipe entirely.
//  - sW1 double-buffered via async DMA; ONE barrier per kc whose vmcnt drain
//    waits on a DMA issued a full iteration earlier (truly hidden).
//  - sH wave-private (no second barrier). LDS = 32+16 = 48 KB.
//  - acc2 = 128 VGPRs -> 2 waves/SIMD; ILP + 3-pipe overlap carries it.
// ---------------------------------------------------------------------------
__global__ __launch_bounds__(256, 2)
void mlp_kernel(const float* __restrict__ x,
                const int*   __restrict__ gidx,
                const bf16*  __restrict__ W1F,
                const float* __restrict__ b1,
                const bf16*  __restrict__ W2F,
                const float* __restrict__ b2,
                bf16*        __restrict__ NF)
{
    __shared__ __align__(16) bf16 sW1[2][8192]; // dbuf: [ks(4)*4+nt(4)][lane][8]
    __shared__ __align__(16) bf16 sH[8192];     // [wave(4)][mt(2)*2+ks2(2)][lane][8]

    const int tid  = threadIdx.x;
    const int bid  = blockIdx.x;
    const int g    = bid >> 9;
    const int rem  = bid & 511;
    const int m0   = (rem >> 1) * 128;
    const int n0t2 = rem & 1;

    const int wave = tid >> 6;
    const int lane = tid & 63;
    const int quad = lane >> 4;
    const int ln   = lane & 15;

    const int*  gI  = gidx + g * NPG + m0;
    const bf16* W1g = W1F + (size_t)g * 131072;                   // [kc][8192]
    const bf16* W2g = W2F + (size_t)(g * 2 + n0t2) * 262144;      // [kc][16384]
    const float* b1g = b1 + g * KEXP;
    const float* b2g = b2 + g * H_DIM + n0t2 * 256;

    // ---- gather x A-frags straight into registers (reused all 16 kc) ----
    bf16x8 xf[8];
    #pragma unroll
    for (int i = 0; i < 8; ++i) {
        int row  = wave * 32 + (i >> 2) * 16 + ln;
        int node = gI[row];
        const float* src = x + (size_t)node * D_IN + (i & 3) * 32 + quad * 8;
        float4 a = *(const float4*)src;
        float4 b = *(const float4*)(src + 4);
        bf16x8 v;
        v[0] = (bf16)a.x; v[1] = (bf16)a.y; v[2] = (bf16)a.z; v[3] = (bf16)a.w;
        v[4] = (bf16)b.x; v[5] = (bf16)b.y; v[6] = (bf16)b.z; v[7] = (bf16)b.w;
        xf[i] = v;
    }

    f32x4 acc2[2][16];
    #pragma unroll
    for (int a = 0; a < 2; ++a)
        #pragma unroll
        for (int b = 0; b < 16; ++b)
            acc2[a][b] = (f32x4){0.f, 0.f, 0.f, 0.f};

    // ---- preloop: DMA chunk 0 into buf 0 ----
    #pragma unroll
    for (int r = 0; r < 4; ++r) {
        int c = r * 4 + wave;
        cp16_async(W1g + c * 512 + lane * 8, sW1[0] + c * 512);
    }

    #pragma unroll 1
    for (int kc = 0; kc < 16; ++kc) {
        __syncthreads();   // drains DMA(kc) (issued one iter ago) + frees other buf

        // ---- prefetch next W1 chunk into the other buffer ----
        {
            int nkc = (kc + 1) & 15;               // wrap: harmless refetch
            const bf16* w1src = W1g + (size_t)nkc * 8192;
            bf16* dstb = sW1[(kc + 1) & 1];
            #pragma unroll
            for (int r = 0; r < 4; ++r) {
                int c = r * 4 + wave;
                cp16_async(w1src + c * 512 + lane * 8, dstb + c * 512);
            }
        }
        const bf16* w1buf = sW1[kc & 1];

        // ---- stage 1: h[wave rows 32][k' 64] = relu(x @ W1c + b1) ----
        float bias_v[4];
        #pragma unroll
        for (int nt = 0; nt < 4; ++nt)
            bias_v[nt] = b1g[kc * 64 + nt * 16 + ln];

        f32x4 acc1[2][4];
        #pragma unroll
        for (int a = 0; a < 2; ++a)
            #pragma unroll
            for (int b = 0; b < 4; ++b)
                acc1[a][b] = (f32x4){0.f, 0.f, 0.f, 0.f};

        #pragma unroll
        for (int ks = 0; ks < 4; ++ks) {
            #pragma unroll
            for (int nt = 0; nt < 4; ++nt) {
                bf16x8 bfr = *(const bf16x8*)(w1buf + ((ks * 4 + nt) * 64 + lane) * 8);
                #pragma unroll
                for (int mt = 0; mt < 2; ++mt)
                    acc1[mt][nt] = __builtin_amdgcn_mfma_f32_16x16x32_bf16(
                        xf[mt * 4 + ks], bfr, acc1[mt][nt], 0, 0, 0);
            }
        }

        // bias+relu -> sH in fragment order (wave-private; no barrier needed)
        #pragma unroll
        for (int nt = 0; nt < 4; ++nt) {
            float bias = bias_v[nt];
            int base = wave * 2048 + ((nt & 1) * 2 + (ln >> 3)) * 128
                     + quad * 32 + (ln & 7);
            #pragma unroll
            for (int mt = 0; mt < 2; ++mt) {
                int fb = base + (mt * 2 + (nt >> 1)) * 512;
                #pragma unroll
                for (int reg = 0; reg < 4; ++reg) {
                    float v = acc1[mt][nt][reg] + bias;
                    sH[fb + reg * 8] = (bf16)fmaxf(v, 0.f);
                }
            }
        }

        // ---- stage 2: og += h @ W2c ; W2 B-frags DIRECT from global ----
        const bf16* w2kc = W2g + (size_t)kc * 16384;
        #pragma unroll
        for (int ks2 = 0; ks2 < 2; ++ks2) {
            bf16x8 a2[2];
            #pragma unroll
            for (int mt = 0; mt < 2; ++mt)
                a2[mt] = *(const bf16x8*)(sH + (wave * 2048) + ((mt * 2 + ks2) * 64 + lane) * 8);
            #pragma unroll
            for (int nt = 0; nt < 16; ++nt) {
                bf16x8 bb = *(const bf16x8*)(w2kc + ((ks2 * 16 + nt) * 64 + lane) * 8);
                #pragma unroll
                for (int mt = 0; mt < 2; ++mt)
                    acc2[mt][nt] = __builtin_amdgcn_mfma_f32_16x16x32_bf16(
                        a2[mt], bb, acc2[mt][nt], 0, 0, 0);
            }
        }
    }

    // ---- epilogue: + b2, scatter rows to NF[node][H] as bf16 ----
    float b2v[16];
    #pragma unroll
    for (int nt = 0; nt < 16; ++nt) b2v[nt] = b2g[nt * 16 + ln];

    #pragma unroll
    for (int mt = 0; mt < 2; ++mt)
        #pragma unroll
        for (int reg = 0; reg < 4; ++reg) {
            int row  = wave * 32 + mt * 16 + quad * 4 + reg;
            int node = gI[row];
            bf16* dst = NF + (size_t)node * H_DIM + n0t2 * 256;
            #pragma unroll
            for (int nt = 0; nt < 16; ++nt)
                dst[nt * 16 + ln] = (bf16)(acc2[mt][nt][reg] + b2v[nt]);
        }
}

// ---------------------------------------------------------------------------
// segment_max over 16 consecutive nodes per fine cluster (sorted arange ids).
// ---------------------------------------------------------------------------
__global__ void pool_kernel(const bf16* __restrict__ NF, float* __restrict__ EMB)
{
    int t  = blockIdx.x * 256 + threadIdx.x;    // 8192*256 total
    int f  = t >> 8;
    int hp = (t & 255) * 2;
    const uint32_t* src = (const uint32_t*)NF;
    size_t base = (size_t)f * 4096 + (hp >> 1);
    float lo = -INFINITY, hi = -INFINITY;
    #pragma unroll
    for (int r = 0; r < 16; ++r) {
        uint32_t v = src[base + (size_t)r * 256];
        lo = fmaxf(lo, __uint_as_float(v << 16));
        hi = fmaxf(hi, __uint_as_float(v & 0xffff0000u));
    }
    *(float2*)(EMB + (size_t)f * 512 + hp) = make_float2(lo, hi);
}

// ---------------------------------------------------------------------------
// Per (coarse group, channel) mean / rsqrt(var+eps) over 256 fine rows.
// ---------------------------------------------------------------------------
__global__ void stats_kernel(const float* __restrict__ EMB,
                             float* __restrict__ MEAN,
                             float* __restrict__ RSIG)
{
    int gc = blockIdx.x;
    int ch = blockIdx.y * 128 + threadIdx.x;
    const float* p = EMB + (size_t)gc * 256 * 512 + ch;
    float s = 0.f, ss = 0.f;
    #pragma unroll 4
    for (int r = 0; r < 256; ++r) {
        float v = p[(size_t)r * 512];
        s += v; ss += v * v;
    }
    float mean = s * (1.f / 256.f);
    float var  = ss * (1.f / 256.f) - mean * mean;
    MEAN[gc * 512 + ch] = mean;
    RSIG[gc * 512 + ch] = rsqrtf(var + 1e-5f);
}

// ---------------------------------------------------------------------------
// logits[f][c] = b_out[c] + sum_h (emb[f][h]-mean)*rsig * w_out[h][c]
// ---------------------------------------------------------------------------
__global__ __launch_bounds__(256)
void classifier_kernel(const float* __restrict__ EMB,
                       const float* __restrict__ MEAN,
                       const float* __restrict__ RSIG,
                       const float* __restrict__ w_out,
                       const float* __restrict__ b_out,
                       float* __restrict__ out)
{
    __shared__ float sW[512 * 16];
    __shared__ float sE[16 * 513];   // +1 pad breaks 4-way bank conflict
    int t  = threadIdx.x;
    int f0 = blockIdx.x * 16;
    int gc = f0 >> 8;

    #pragma unroll
    for (int it = 0; it < 8; ++it) {
        int i = (it * 256 + t) * 4;
        *(float4*)(sW + i) = *(const float4*)(w_out + i);
    }
    #pragma unroll
    for (int it = 0; it < 32; ++it) {
        int i  = it * 256 + t;
        int fr = i >> 9;
        int h  = i & 511;
        float v = EMB[(size_t)(f0 + fr) * 512 + h];
        sE[fr * 513 + h] = (v - MEAN[gc * 512 + h]) * RSIG[gc * 512 + h];
    }
    __syncthreads();

    int fr = t >> 4;
    int c  = t & 15;
    float acc = b_out[c];
    #pragma unroll 8
    for (int h = 0; h < 512; ++h)
        acc += sE[fr * 513 + h] * sW[h * 16 + c];
    out[(size_t)(f0 + fr) * 16 + c] = acc;
}

// ---------------------------------------------------------------------------
// Workspace layout (~156.4 MB):
//   W1F 1 MB | W2F 4 MB | NF 134 MB | EMB 16 MB | MEAN 64K | RSIG 64K
// ---------------------------------------------------------------------------
extern "C" void kernel_launch(void* const* d_in, const int* in_sizes, int n_in,
                              void* d_out, int out_size, void* d_ws, size_t ws_size,
                              hipStream_t stream)
{
    const float* x     = (const float*)d_in[0];
    const int*   gidx  = (const int*)d_in[1];
    const float* W1    = (const float*)d_in[4];
    const float* b1    = (const float*)d_in[5];
    const float* W2    = (const float*)d_in[6];
    const float* b2    = (const float*)d_in[7];
    const float* w_out = (const float*)d_in[8];
    const float* b_out = (const float*)d_in[9];
    float* out = (float*)d_out;

    char* w = (char*)d_ws;
    bf16* W1F = (bf16*)w;  w += (size_t)NGRP * KEXP * D_IN * 2;
    bf16* W2F = (bf16*)w;  w += (size_t)NGRP * H_DIM * KEXP * 2;
    bf16* NF  = (bf16*)w;  w += (size_t)N_NODES * H_DIM * 2;
    float* EMB  = (float*)w; w += (size_t)F_SEG * H_DIM * 4;
    float* MEAN = (float*)w; w += (size_t)G_SEG * H_DIM * 4;
    float* RSIG = (float*)w; w += (size_t)G_SEG * H_DIM * 4;

    convert_weights<<<1280, 256, 0, stream>>>(W1, W2, W1F, W2F);
    mlp_kernel<<<2048, 256, 0, stream>>>(x, gidx, W1F, b1, W2F, b2, NF);
    pool_kernel<<<8192, 256, 0, stream>>>(NF, EMB);
    stats_kernel<<<dim3(32, 4), 128, 0, stream>>>(EMB, MEAN, RSIG);
    classifier_kernel<<<512, 256, 0, stream>>>(EMB, MEAN, RSIG, w_out, b_out, out);
}

// Round 5
// 387.458 us; speedup vs baseline: 1.4104x; 1.4104x over previous
//
#include <hip/hip_runtime.h>
#include <stdint.h>

typedef __bf16 bf16;
typedef bf16 bf16x8 __attribute__((ext_vector_type(8)));
typedef float f32x4 __attribute__((ext_vector_type(4)));

#define N_NODES 131072
#define D_IN    128
#define KEXP    1024
#define H_DIM   512
#define NGRP    4
#define NPG     32768   // N_NODES / NGRP
#define F_SEG   8192
#define G_SEG   32
#define C_OUT   16

// async global->LDS DMA, 16B per lane; LDS dest = wave-uniform base + lane*16
typedef const __attribute__((address_space(1))) void* gas_t;
typedef __attribute__((address_space(3))) void* las_t;
__device__ __forceinline__ void cp16_async(const bf16* g, bf16* l) {
    __builtin_amdgcn_global_load_lds((gas_t)g, (las_t)l, 16, 0, 0);
}

// ---------------------------------------------------------------------------
// One-time weight cast + swizzle into MFMA-fragment order (16x16x32 bf16).
// B-frag: lane (quad=lane>>4, ln=lane&15) holds B[k=quad*8+j][n=ln].
// K-chunk = 32 (kc in [0,32)); N-tile = 256 (n0t2 in [0,2)).
//
// W1F[g][kc(32)][f=ks*2+nt (8)][lane(64)][j(8)]
//     = W1[g][d = ks*32 + quad*8 + j][k' = kc*32 + nt*16 + ln]
// W2F[g][n0t2(2)][kc(32)][f=nt (16)][lane][j]
//     = W2[g][k = kc*32 + quad*8 + j][n = n0t2*256 + nt*16 + ln]
// ---------------------------------------------------------------------------
__global__ void convert_weights(const float* __restrict__ W1,
                                const float* __restrict__ W2,
                                bf16* __restrict__ W1F,
                                bf16* __restrict__ W2F)
{
    int t = blockIdx.x * 256 + threadIdx.x;
    if (t < 65536) {
        int slot = t & 63, f = (t >> 6) & 7, kc = (t >> 9) & 31, g = t >> 14;
        int ks = f >> 1, nt = f & 1, quad = slot >> 4, ln = slot & 15;
        int k = kc * 32 + nt * 16 + ln;
        const float* src = W1 + ((size_t)(g * 128 + ks * 32 + quad * 8)) * 1024 + k;
        bf16x8 v;
        #pragma unroll
        for (int j = 0; j < 8; ++j) v[j] = (bf16)src[(size_t)j * 1024];
        *(bf16x8*)(W1F + (size_t)t * 8) = v;
    } else {
        int u = t - 65536;
        if (u < 262144) {
            int slot = u & 63, f = (u >> 6) & 15, kc = (u >> 10) & 31;
            int n0t2 = (u >> 15) & 1, g = u >> 16;
            int quad = slot >> 4, ln = slot & 15;
            int k = kc * 32 + quad * 8;
            int n = n0t2 * 256 + f * 16 + ln;
            const float* src = W2 + ((size_t)(g * 1024 + k)) * 512 + n;
            bf16x8 v;
            #pragma unroll
            for (int j = 0; j < 8; ++j) v[j] = (bf16)src[(size_t)j * 512];
            *(bf16x8*)(W2F + (size_t)u * 8) = v;
        }
    }
}

// ---------------------------------------------------------------------------
// Fused gather + GEMM1(relu) + GEMM2 + scatter. 256 threads (4 waves).
// Round-5: tile 128 nodes x 256 of H, K-chunk 32, BOTH weight buffers
// double-buffered in LDS via async DMA. ONE barrier per kc; prefetch for
// kc+1 is issued right after the barrier into the other buffer, so the
// vmcnt(0) drain at the NEXT barrier waits on a DMA that had a full compute
// iteration to fly (round-3 exposed it; round-4's direct-global L2 loads
// stalled every stage-2 MFMA).
// LDS: sW1 2x8K + sW2 2x16K + sH 8K = 56 KB -> 2 blocks/CU.
// sH is wave-private -> no second barrier.
// ---------------------------------------------------------------------------
__global__ __launch_bounds__(256, 2)
void mlp_kernel(const float* __restrict__ x,
                const int*   __restrict__ gidx,
                const bf16*  __restrict__ W1F,
                const float* __restrict__ b1,
                const bf16*  __restrict__ W2F,
                const float* __restrict__ b2,
                bf16*        __restrict__ NF)
{
    __shared__ __align__(16) bf16 sW1[2][4096]; // [f=ks*2+nt (8)][lane][8]
    __shared__ __align__(16) bf16 sW2[2][8192]; // [f=nt (16)][lane][8]
    __shared__ __align__(16) bf16 sH[4096];     // [wave(4)][mt(2)][lane][8]

    const int tid  = threadIdx.x;
    const int bid  = blockIdx.x;
    const int g    = bid >> 9;
    const int rem  = bid & 511;
    const int m0   = (rem >> 1) * 128;
    const int n0t2 = rem & 1;

    const int wave = tid >> 6;
    const int lane = tid & 63;
    const int quad = lane >> 4;
    const int ln   = lane & 15;

    const int*  gI  = gidx + g * NPG + m0;
    const bf16* W1g = W1F + (size_t)g * 131072;                   // [kc][4096]
    const bf16* W2g = W2F + (size_t)(g * 2 + n0t2) * 262144;      // [kc][8192]
    const float* b1g = b1 + g * KEXP;
    const float* b2g = b2 + g * H_DIM + n0t2 * 256;

    // ---- gather x A-frags straight into registers (reused all 32 kc) ----
    // frag i (mt=i>>2, ks=i&3): lane holds x[row=wave*32+mt*16+ln][ks*32+quad*8 ..+8)
    bf16x8 xf[8];
    #pragma unroll
    for (int i = 0; i < 8; ++i) {
        int row  = wave * 32 + (i >> 2) * 16 + ln;
        int node = gI[row];
        const float* src = x + (size_t)node * D_IN + (i & 3) * 32 + quad * 8;
        float4 a = *(const float4*)src;
        float4 b = *(const float4*)(src + 4);
        bf16x8 v;
        v[0] = (bf16)a.x; v[1] = (bf16)a.y; v[2] = (bf16)a.z; v[3] = (bf16)a.w;
        v[4] = (bf16)b.x; v[5] = (bf16)b.y; v[6] = (bf16)b.z; v[7] = (bf16)b.w;
        xf[i] = v;
    }

    f32x4 acc2[2][16];
    #pragma unroll
    for (int a = 0; a < 2; ++a)
        #pragma unroll
        for (int b = 0; b < 16; ++b)
            acc2[a][b] = (f32x4){0.f, 0.f, 0.f, 0.f};

    // ---- preloop: DMA chunk 0 into buf 0 ----
    #pragma unroll
    for (int r = 0; r < 2; ++r) {
        int c = r * 4 + wave;
        cp16_async(W1g + c * 512 + lane * 8, sW1[0] + c * 512);
    }
    #pragma unroll
    for (int r = 0; r < 4; ++r) {
        int c = r * 4 + wave;
        cp16_async(W2g + c * 512 + lane * 8, sW2[0] + c * 512);
    }

    #pragma unroll 1
    for (int kc = 0; kc < 32; ++kc) {
        __syncthreads();   // drains DMA(kc) issued one iter ago; frees buf^1 reads

        // ---- prefetch chunk kc+1 into the other buffer ----
        {
            int nkc = (kc + 1) & 31;               // wrap: harmless refetch
            const bf16* w1src = W1g + (size_t)nkc * 4096;
            const bf16* w2src = W2g + (size_t)nkc * 8192;
            bf16* d1 = sW1[(kc + 1) & 1];
            bf16* d2 = sW2[(kc + 1) & 1];
            #pragma unroll
            for (int r = 0; r < 2; ++r) {
                int c = r * 4 + wave;
                cp16_async(w1src + c * 512 + lane * 8, d1 + c * 512);
            }
            #pragma unroll
            for (int r = 0; r < 4; ++r) {
                int c = r * 4 + wave;
                cp16_async(w2src + c * 512 + lane * 8, d2 + c * 512);
            }
        }
        const bf16* w1buf = sW1[kc & 1];
        const bf16* w2buf = sW2[kc & 1];

        // ---- stage 1: h[wave rows 32][k' 32] = relu(x @ W1c + b1) ----
        float bias_v[2];
        #pragma unroll
        for (int nt = 0; nt < 2; ++nt)
            bias_v[nt] = b1g[kc * 32 + nt * 16 + ln];

        f32x4 acc1[2][2];
        #pragma unroll
        for (int a = 0; a < 2; ++a)
            #pragma unroll
            for (int b = 0; b < 2; ++b)
                acc1[a][b] = (f32x4){0.f, 0.f, 0.f, 0.f};

        #pragma unroll
        for (int ks = 0; ks < 4; ++ks) {
            #pragma unroll
            for (int nt = 0; nt < 2; ++nt) {
                bf16x8 bfr = *(const bf16x8*)(w1buf + ((ks * 2 + nt) * 64 + lane) * 8);
                #pragma unroll
                for (int mt = 0; mt < 2; ++mt)
                    acc1[mt][nt] = __builtin_amdgcn_mfma_f32_16x16x32_bf16(
                        xf[mt * 4 + ks], bfr, acc1[mt][nt], 0, 0, 0);
            }
        }

        // bias+relu -> sH in A-frag order (wave-private; no barrier needed)
        // h[m-local = mt*16 + quad*4+reg][k'-local = nt*16+ln] -> element
        // (frag = wave*2+mt, quad_a = nt*2+(ln>>3), ln_a = quad*4+reg, j = ln&7)
        #pragma unroll
        for (int nt = 0; nt < 2; ++nt) {
            float bias = bias_v[nt];
            int base = wave * 1024 + (nt * 2 + (ln >> 3)) * 128
                     + (quad * 4) * 8 + (ln & 7);
            #pragma unroll
            for (int mt = 0; mt < 2; ++mt) {
                int fb = base + mt * 512;
                #pragma unroll
                for (int reg = 0; reg < 4; ++reg) {
                    float v = acc1[mt][nt][reg] + bias;
                    sH[fb + reg * 8] = (bf16)fmaxf(v, 0.f);
                }
            }
        }

        // ---- stage 2: og += h @ W2c (K=32: one MFMA K-step per kc) ----
        bf16x8 a2[2];
        #pragma unroll
        for (int mt = 0; mt < 2; ++mt)
            a2[mt] = *(const bf16x8*)(sH + wave * 1024 + mt * 512 + lane * 8);
        #pragma unroll
        for (int nt = 0; nt < 16; ++nt) {
            bf16x8 bb = *(const bf16x8*)(w2buf + (nt * 64 + lane) * 8);
            #pragma unroll
            for (int mt = 0; mt < 2; ++mt)
                acc2[mt][nt] = __builtin_amdgcn_mfma_f32_16x16x32_bf16(
                    a2[mt], bb, acc2[mt][nt], 0, 0, 0);
        }
    }

    // ---- epilogue: + b2, scatter rows to NF[node][H] as bf16 ----
    float b2v[16];
    #pragma unroll
    for (int nt = 0; nt < 16; ++nt) b2v[nt] = b2g[nt * 16 + ln];

    #pragma unroll
    for (int mt = 0; mt < 2; ++mt)
        #pragma unroll
        for (int reg = 0; reg < 4; ++reg) {
            int row  = wave * 32 + mt * 16 + quad * 4 + reg;
            int node = gI[row];
            bf16* dst = NF + (size_t)node * H_DIM + n0t2 * 256;
            #pragma unroll
            for (int nt = 0; nt < 16; ++nt)
                dst[nt * 16 + ln] = (bf16)(acc2[mt][nt][reg] + b2v[nt]);
        }
}

// ---------------------------------------------------------------------------
// segment_max over 16 consecutive nodes per fine cluster (sorted arange ids).
// ---------------------------------------------------------------------------
__global__ void pool_kernel(const bf16* __restrict__ NF, float* __restrict__ EMB)
{
    int t  = blockIdx.x * 256 + threadIdx.x;    // 8192*256 total
    int f  = t >> 8;
    int hp = (t & 255) * 2;
    const uint32_t* src = (const uint32_t*)NF;
    size_t base = (size_t)f * 4096 + (hp >> 1);
    float lo = -INFINITY, hi = -INFINITY;
    #pragma unroll
    for (int r = 0; r < 16; ++r) {
        uint32_t v = src[base + (size_t)r * 256];
        lo = fmaxf(lo, __uint_as_float(v << 16));
        hi = fmaxf(hi, __uint_as_float(v & 0xffff0000u));
    }
    *(float2*)(EMB + (size_t)f * 512 + hp) = make_float2(lo, hi);
}

// ---------------------------------------------------------------------------
// Per (coarse group, channel) mean / rsqrt(var+eps) over 256 fine rows.
// ---------------------------------------------------------------------------
__global__ void stats_kernel(const float* __restrict__ EMB,
                             float* __restrict__ MEAN,
                             float* __restrict__ RSIG)
{
    int gc = blockIdx.x;
    int ch = blockIdx.y * 128 + threadIdx.x;
    const float* p = EMB + (size_t)gc * 256 * 512 + ch;
    float s = 0.f, ss = 0.f;
    #pragma unroll 4
    for (int r = 0; r < 256; ++r) {
        float v = p[(size_t)r * 512];
        s += v; ss += v * v;
    }
    float mean = s * (1.f / 256.f);
    float var  = ss * (1.f / 256.f) - mean * mean;
    MEAN[gc * 512 + ch] = mean;
    RSIG[gc * 512 + ch] = rsqrtf(var + 1e-5f);
}

// ---------------------------------------------------------------------------
// logits[f][c] = b_out[c] + sum_h (emb[f][h]-mean)*rsig * w_out[h][c]
// ---------------------------------------------------------------------------
__global__ __launch_bounds__(256)
void classifier_kernel(const float* __restrict__ EMB,
                       const float* __restrict__ MEAN,
                       const float* __restrict__ RSIG,
                       const float* __restrict__ w_out,
                       const float* __restrict__ b_out,
                       float* __restrict__ out)
{
    __shared__ float sW[512 * 16];
    __shared__ float sE[16 * 513];   // +1 pad breaks 4-way bank conflict
    int t  = threadIdx.x;
    int f0 = blockIdx.x * 16;
    int gc = f0 >> 8;

    #pragma unroll
    for (int it = 0; it < 8; ++it) {
        int i = (it * 256 + t) * 4;
        *(float4*)(sW + i) = *(const float4*)(w_out + i);
    }
    #pragma unroll
    for (int it = 0; it < 32; ++it) {
        int i  = it * 256 + t;
        int fr = i >> 9;
        int h  = i & 511;
        float v = EMB[(size_t)(f0 + fr) * 512 + h];
        sE[fr * 513 + h] = (v - MEAN[gc * 512 + h]) * RSIG[gc * 512 + h];
    }
    __syncthreads();

    int fr = t >> 4;
    int c  = t & 15;
    float acc = b_out[c];
    #pragma unroll 8
    for (int h = 0; h < 512; ++h)
        acc += sE[fr * 513 + h] * sW[h * 16 + c];
    out[(size_t)(f0 + fr) * 16 + c] = acc;
}

// ---------------------------------------------------------------------------
// Workspace layout (~156.4 MB):
//   W1F 1 MB | W2F 4 MB | NF 134 MB | EMB 16 MB | MEAN 64K | RSIG 64K
// ---------------------------------------------------------------------------
extern "C" void kernel_launch(void* const* d_in, const int* in_sizes, int n_in,
                              void* d_out, int out_size, void* d_ws, size_t ws_size,
                              hipStream_t stream)
{
    const float* x     = (const float*)d_in[0];
    const int*   gidx  = (const int*)d_in[1];
    const float* W1    = (const float*)d_in[4];
    const float* b1    = (const float*)d_in[5];
    const float* W2    = (const float*)d_in[6];
    const float* b2    = (const float*)d_in[7];
    const float* w_out = (const float*)d_in[8];
    const float* b_out = (const float*)d_in[9];
    float* out = (float*)d_out;

    char* w = (char*)d_ws;
    bf16* W1F = (bf16*)w;  w += (size_t)NGRP * KEXP * D_IN * 2;
    bf16* W2F = (bf16*)w;  w += (size_t)NGRP * H_DIM * KEXP * 2;
    bf16* NF  = (bf16*)w;  w += (size_t)N_NODES * H_DIM * 2;
    float* EMB  = (float*)w; w += (size_t)F_SEG * H_DIM * 4;
    float* MEAN = (float*)w; w += (size_t)G_SEG * H_DIM * 4;
    float* RSIG = (float*)w; w += (size_t)G_SEG * H_DIM * 4;

    convert_weights<<<1280, 256, 0, stream>>>(W1, W2, W1F, W2F);
    mlp_kernel<<<2048, 256, 0, stream>>>(x, gidx, W1F, b1, W2F, b2, NF);
    pool_kernel<<<8192, 256, 0, stream>>>(NF, EMB);
    stats_kernel<<<dim3(32, 4), 128, 0, stream>>>(EMB, MEAN, RSIG);
    classifier_kernel<<<512, 256, 0, stream>>>(EMB, MEAN, RSIG, w_out, b_out, out);
}